// Round 6
// baseline (207.305 us; speedup 1.0000x reference)
//
#include <hip/hip_runtime.h>
#include <hip/hip_bf16.h>

#define BB 2
#define LL 2048
#define EE 768
#define HH 12
#define DD 64
#define N3 2304
#define TOK 4096   // BB*LL
#define LOG2E 1.4426950408889634f

typedef __attribute__((ext_vector_type(8))) short short8;
typedef __attribute__((ext_vector_type(4))) short s16x4;
typedef __attribute__((ext_vector_type(4))) float f32x4;
typedef __attribute__((ext_vector_type(4))) unsigned int uix4;
typedef unsigned int uint_t;
typedef unsigned short ushort_t;

__device__ __forceinline__ f32x4 mfma16(short8 a, short8 b, f32x4 c) {
  return __builtin_amdgcn_mfma_f32_16x16x32_bf16(a, b, c, 0, 0, 0);
}
// K=16 bf16 MFMA: B-layout B[k=quad*4+j][n=c16] == S^T C-layout -> P is a
// zero-cost B operand.
__device__ __forceinline__ f32x4 mfma16k16(s16x4 a, s16x4 b, f32x4 c) {
  return __builtin_amdgcn_mfma_f32_16x16x16bf16_1k(a, b, c, 0, 0, 0);
}

__device__ __forceinline__ ushort_t bf16bits(float f) {
  __hip_bfloat16 h = __float2bfloat16(f);
  return *reinterpret_cast<ushort_t*>(&h);
}

// raw v_exp_f32 (base-2 exp), avoids OCML multi-instruction expansion
__device__ __forceinline__ float fast_exp2(float x) {
  float r;
  asm("v_exp_f32 %0, %1" : "=v"(r) : "v"(x));
  return r;
}

// cheap unbiased-enough bf16 pair pack: round-half-up via +0x8000, truncate
__device__ __forceinline__ uint_t pack2bf_rn(float a, float b) {
  uint_t ua = __float_as_uint(a) + 0x8000u;
  uint_t ub = __float_as_uint(b) + 0x8000u;
  return (ua >> 16) | (ub & 0xFFFF0000u);
}

__device__ __forceinline__ float bits2f(ushort_t u) {
  union { uint_t u; float f; } cv;
  cv.u = ((uint_t)u) << 16;
  return cv.f;
}

// ---- global -> LDS staging, 16 KB tile, XOR-swizzled 16B chunks (GEMMs) --
__device__ __forceinline__ void stage64(const __hip_bfloat16* gbase, int ldg,
                                        short* lds, int tid) {
  const int wave = tid >> 6, lane = tid & 63;
#pragma unroll
  for (int c = 0; c < 4; ++c) {
    int off = c * 4096 + wave * 1024 + lane * 16;   // byte offset in tile
    int row = off >> 7;
    int cs  = (off & 127) >> 4;
    int cc  = cs ^ (row & 7);
    __builtin_amdgcn_global_load_lds(
        (const __attribute__((address_space(1))) void*)((const short*)gbase + (size_t)row * ldg + cc * 8),
        (__attribute__((address_space(3))) void*)(lds + c * 2048 + wave * 512),
        16, 0, 0);
  }
}

__device__ __forceinline__ short8 frag64(const short* lds, int row, int chunk) {
  return *(const short8*)(lds + row * 64 + (chunk ^ (row & 7)) * 8);
}

// ---- prep: LDS-tiled transpose + LoRA fold -> w1T/w2T; coalesced x cast --
__global__ void prep_kernel(const float* __restrict__ x, const float* __restrict__ w_in,
                            const float* __restrict__ A_in, const float* __restrict__ B_in,
                            const float* __restrict__ w_out, const float* __restrict__ A_out,
                            const float* __restrict__ B_out,
                            __hip_bfloat16* __restrict__ xb, __hip_bfloat16* __restrict__ w1T,
                            __hip_bfloat16* __restrict__ w2T) {
  __shared__ float tile[32][33];
  const int bid = blockIdx.x, t = threadIdx.x;
  if (bid < 2304) {
    const float *W, *Am, *Bm;
    __hip_bfloat16* out;
    int N, tx, ty;
    if (bid < 1728) { W = w_in;  Am = A_in;  Bm = B_in;  out = w1T; N = N3; tx = bid % 72; ty = bid / 72; }
    else { int jj = bid - 1728; W = w_out; Am = A_out; Bm = B_out; out = w2T; N = EE; tx = jj % 24; ty = jj / 24; }
    const int e0 = ty * 32, o0 = tx * 32;
    const int r = t >> 5, col = t & 31;
#pragma unroll
    for (int i = 0; i < 4; ++i)
      tile[r + i * 8][col] = W[(size_t)(e0 + r + i * 8) * N + (o0 + col)];
    __syncthreads();
    const int e = e0 + col;
    const float b0 = Bm[e * 4 + 0], b1 = Bm[e * 4 + 1], b2 = Bm[e * 4 + 2], b3 = Bm[e * 4 + 3];
#pragma unroll
    for (int i = 0; i < 4; ++i) {
      const int o = o0 + r + i * 8;
      float acc = b0 * Am[o] + b1 * Am[N + o] + b2 * Am[2 * N + o] + b3 * Am[3 * N + o];
      out[(size_t)o * EE + e] = __float2bfloat16(tile[col][r + i * 8] + 8.0f * acc);
    }
  } else {
    const int j = bid - 2304;              // 768 blocks x 4096 f32 each
    const float* src = x + (size_t)j * 4096 + t * 16;
    short* dst = (short*)xb + (size_t)j * 4096 + t * 16;
#pragma unroll
    for (int half = 0; half < 2; ++half) {
      float4 a = ((const float4*)src)[half * 2];
      float4 b = ((const float4*)src)[half * 2 + 1];
      short8 v;
      v[0] = (short)bf16bits(a.x); v[1] = (short)bf16bits(a.y);
      v[2] = (short)bf16bits(a.z); v[3] = (short)bf16bits(a.w);
      v[4] = (short)bf16bits(b.x); v[5] = (short)bf16bits(b.y);
      v[6] = (short)bf16bits(b.z); v[7] = (short)bf16bits(b.w);
      ((short8*)dst)[half] = v;
    }
  }
}

// ---- GEMM: C[M,N] = A[M,K] @ BT[N,K]^T + bias, 128x128 tile, BK=64 -------
// QSCALE: scale cols n<EE by log2e. SPLITV: cols n>=2E are written
// TRANSPOSED into vT[b*768 + (n-2E)][l] instead of row-major outp.
template<bool F32OUT, bool QSCALE, bool SPLITV>
__global__ __launch_bounds__(256, 2) void gemm_bt(const __hip_bfloat16* __restrict__ A,
                                                  const __hip_bfloat16* __restrict__ BT,
                                                  const float* __restrict__ bias,
                                                  void* __restrict__ outp,
                                                  __hip_bfloat16* __restrict__ vTp,
                                                  int M, int N, int K) {
  __shared__ __align__(16) short Al[128 * 64];
  __shared__ __align__(16) short Bl[128 * 64];
  const int tid = threadIdx.x, lane = tid & 63, wave = tid >> 6;
  const int quad = lane >> 4, c16 = lane & 15;
  const int n0 = blockIdx.x * 128, m0 = blockIdx.y * 128;
  const int msub = (wave & 1) * 64, nsub = (wave >> 1) * 64;
  f32x4 acc[4][4] = {};
  for (int k0 = 0; k0 < K; k0 += 64) {
    __syncthreads();
    stage64(A + (size_t)m0 * K + k0, K, Al, tid);
    stage64(BT + (size_t)n0 * K + k0, K, Bl, tid);
    __syncthreads();
#pragma unroll
    for (int ks = 0; ks < 2; ++ks) {
      short8 af[4], bfr[4];
#pragma unroll
      for (int i = 0; i < 4; ++i) {
        af[i]  = frag64(Al, msub + i * 16 + c16, ks * 4 + quad);
        bfr[i] = frag64(Bl, nsub + i * 16 + c16, ks * 4 + quad);
      }
#pragma unroll
      for (int mi = 0; mi < 4; ++mi)
#pragma unroll
        for (int ni = 0; ni < 4; ++ni)
          acc[mi][ni] = mfma16(af[mi], bfr[ni], acc[mi][ni]);
    }
  }
  if (SPLITV && n0 >= 2 * EE) {          // V block: transposed scatter to vT
    const int bofs = (m0 >> 11) * EE;    // b*768
    const int l0 = (m0 & 2047) + msub;
#pragma unroll
    for (int ni = 0; ni < 4; ++ni) {
      int n = n0 + nsub + ni * 16 + c16;
      float bv = bias[n];
      const size_t rowbase = (size_t)(bofs + (n - 2 * EE)) * LL;
#pragma unroll
      for (int mi = 0; mi < 4; ++mi) {
        int l = l0 + mi * 16 + quad * 4;
        uint2 w;
        w.x = pack2bf_rn(acc[mi][ni][0] + bv, acc[mi][ni][1] + bv);
        w.y = pack2bf_rn(acc[mi][ni][2] + bv, acc[mi][ni][3] + bv);
        *(uint2*)((short*)vTp + rowbase + l) = w;
      }
    }
    return;
  }
#pragma unroll
  for (int ni = 0; ni < 4; ++ni) {
    int n = n0 + nsub + ni * 16 + c16;
    float bv = bias[n];
    float sc = (QSCALE && n < EE) ? LOG2E : 1.0f;
#pragma unroll
    for (int mi = 0; mi < 4; ++mi) {
      int row0 = m0 + msub + mi * 16 + quad * 4;
#pragma unroll
      for (int r = 0; r < 4; ++r) {
        float v = (acc[mi][ni][r] + bv) * sc;
        if (F32OUT) ((float*)outp)[(size_t)(row0 + r) * N + n] = v;
        else ((__hip_bfloat16*)outp)[(size_t)(row0 + r) * N + n] = __float2bfloat16(v);
      }
    }
  }
}

// ---- split-K flash attention, barrier-free, registers-from-global --------
// Block = (b,h, 128-q tile, 512-token k-chunk); 40 (qt,cch) slots per bh,
// heavy-first. No K/V LDS, no __syncthreads: K/V fragments load straight
// from global (L2/L3-served), compiler issues fine-grained vmcnt per use.
// qt<4 writes normalized output to abuf; others write partials to Opart.
#define SLOT_BYTES 16896   // 128*64*2 (O) + 128*4 (l)
union pk4 { uint_t u[2]; s16x4 s4; };

__device__ const signed char QTAB[40] = {
  3,4,5,6,7,8,9,10,11,12,13,14,15,  7,8,9,10,11,12,13,14,15,
  11,12,13,14,15, 15,  2,6,10,14,  1,5,9,13,  0,4,8,12};
__device__ const signed char CTAB[40] = {
  0,0,0,0,0,0,0,0,0,0,0,0,0,  1,1,1,1,1,1,1,1,1,
  2,2,2,2,2, 3,  0,1,2,3,  0,1,2,3,  0,1,2,3};

__global__ __launch_bounds__(256, 4) void attn_kernel(const __hip_bfloat16* __restrict__ qkv,
                                                      const __hip_bfloat16* __restrict__ vT,
                                                      char* __restrict__ Opart,
                                                      __hip_bfloat16* __restrict__ abuf) {
  __shared__ __align__(16) short Ep[4 * 1152];   // per-wave epilogue scratch
  const int tid = threadIdx.x, lane = tid & 63, wave = tid >> 6;
  const int quad = lane >> 4, c16 = lane & 15;
  const int bid = blockIdx.x;
  const int bh = bid % 24;
  const int j = bid / 24;
  const int qt = QTAB[j], cch = CTAB[j];
  const int b = bh / HH, h = bh % HH;
  const int q0 = qt * 128;
  const int qw = q0 + wave * 32;        // wave's first q row (A half)
  const int ks = cch * 512;
  const int ke = min(q0 + 128, ks + 512);
  const int niter = (ke - ks + 127) >> 7;
  short8 qfA[2], qfB[2];
  {
    const short* qra = (const short*)qkv + (size_t)(b * LL + qw + c16) * N3 + h * DD;
    qfA[0] = *(const short8*)(qra + quad * 8);
    qfA[1] = *(const short8*)(qra + 32 + quad * 8);
    const short* qrb = qra + 16 * N3;
    qfB[0] = *(const short8*)(qrb + quad * 8);
    qfB[1] = *(const short8*)(qrb + 32 + quad * 8);
  }
  float lA = 0.f, lB = 0.f;
  f32x4 oA[4] = {}, oB[4] = {};         // O^T: d = dt*16+quad*4+r, q = c16
  // lane-fixed global base pointers
  const short* kg = (const short*)qkv + (size_t)(b * LL + c16) * N3 + EE + h * DD + quad * 8;
  const short* vg = (const short*)vT + (size_t)((b * HH + h) * DD + c16) * LL + quad * 4;
  for (int it = 0; it < niter; ++it) {
    const int k0 = ks + it * 128;
    int nlimB = (qw + 31 - k0) / 16 + 1; if (nlimB > 8) nlimB = 8;
    int nlimA = (qw + 15 - k0) / 16 + 1; if (nlimA > 8) nlimA = 8;
#pragma unroll
    for (int nt = 0; nt < 8; ++nt) {
      if (nt < nlimB) {
        const short* kr = kg + (size_t)(k0 + nt * 16) * N3;   // row k0+nt*16+c16
        short8 kf0 = *(const short8*)(kr);
        short8 kf1 = *(const short8*)(kr + 32);
        const int kb = k0 + nt * 16 + quad * 4;
        const bool diag = (k0 + nt * 16 + 15 > qw + 16);
        f32x4 sB = {};
        sB = mfma16(kf0, qfB[0], sB);
        sB = mfma16(kf1, qfB[1], sB);
        if (diag) {
          const int q = qw + 16 + c16;
#pragma unroll
          for (int r = 0; r < 4; ++r)
            if (kb + r > q) sB[r] = -1e9f;
        }
        pk4 pB;
        {
          float p0 = fast_exp2(sB[0]), p1 = fast_exp2(sB[1]);
          float p2 = fast_exp2(sB[2]), p3 = fast_exp2(sB[3]);
          lB += (p0 + p1) + (p2 + p3);
          pB.u[0] = pack2bf_rn(p0, p1);
          pB.u[1] = pack2bf_rn(p2, p3);
        }
        const bool doA = (nt < nlimA);
        pk4 pA;
        if (doA) {
          f32x4 sA = {};
          sA = mfma16(kf0, qfA[0], sA);
          sA = mfma16(kf1, qfA[1], sA);
          if (k0 + nt * 16 + 15 > qw) {
            const int q = qw + c16;
#pragma unroll
            for (int r = 0; r < 4; ++r)
              if (kb + r > q) sA[r] = -1e9f;
          }
          float p0 = fast_exp2(sA[0]), p1 = fast_exp2(sA[1]);
          float p2 = fast_exp2(sA[2]), p3 = fast_exp2(sA[3]);
          lA += (p0 + p1) + (p2 + p3);
          pA.u[0] = pack2bf_rn(p0, p1);
          pA.u[1] = pack2bf_rn(p2, p3);
        }
        // PV: A-frag = V^T[d = dt*16+c16][k0+nt*16+quad*4 ..+3], 8 B loads
        const short* vb = vg + k0 + nt * 16;
#pragma unroll
        for (int dt = 0; dt < 4; ++dt) {
          s16x4 vf = *(const s16x4*)(vb + (size_t)dt * 16 * LL);
          oB[dt] = mfma16k16(vf, pB.s4, oB[dt]);
          if (doA) oA[dt] = mfma16k16(vf, pA.s4, oA[dt]);
        }
      }
    }
  }
  lA += __shfl_xor(lA, 16); lA += __shfl_xor(lA, 32);
  lB += __shfl_xor(lB, 16); lB += __shfl_xor(lB, 32);
  const bool single = (cch == 0) && (qt < 4);
  const float nA = single ? 1.0f / lA : 1.0f;
  const float nB = single ? 1.0f / lB : 1.0f;
  char* op = Opart + (size_t)((bh * 16 + qt) * 4 + cch) * SLOT_BYTES;
  if (!single && quad == 0) {
    float* lout = (float*)(op + 16384);
    lout[wave * 32 + c16] = lA;
    lout[wave * 32 + 16 + c16] = lB;
  }
  // per-wave LDS transpose (same-wave only -> no barrier needed)
  short* reg = Ep + wave * 1152;        // 16 q x 72-short rows (private)
#pragma unroll
  for (int hh = 0; hh < 2; ++hh) {
    const float sc = hh ? nB : nA;
#pragma unroll
    for (int dt = 0; dt < 4; ++dt) {
      f32x4 o = hh ? oB[dt] : oA[dt];
      uint_t* p = (uint_t*)(reg + c16 * 72 + dt * 16 + quad * 4);
      p[0] = pack2bf_rn(o[0] * sc, o[1] * sc);
      p[1] = pack2bf_rn(o[2] * sc, o[3] * sc);
    }
#pragma unroll
    for (int it = 0; it < 2; ++it) {
      int idx = it * 64 + lane;
      int tq = idx >> 3, c = idx & 7;
      short8 v = *(const short8*)(reg + tq * 72 + c * 8);
      if (single)
        *(short8*)((short*)abuf + (size_t)(b * LL + q0 + wave * 32 + hh * 16 + tq) * EE + h * DD + c * 8) = v;
      else
        *(short8*)((short*)op + (wave * 32 + hh * 16 + tq) * 64 + c * 8) = v;
    }
  }
}

// ---- merge (qt>=4): sum nch=qt/4+1 partials, normalize, write abuf -------
__global__ void merge_kernel(const char* __restrict__ Opart,
                             __hip_bfloat16* __restrict__ abuf) {
  const int t = threadIdx.x;
  const int bh = blockIdx.x / 12, qt = 4 + (blockIdx.x % 12);
  const int nch = (qt >> 2) + 1;
  const int b = bh / HH, h = bh % HH;
  const char* pb = Opart + (size_t)((bh * 16 + qt) * 4) * SLOT_BYTES;
  const int q = t >> 1, dc = (t & 1) * 32;
  float l = 0.f;
  float acc[32];
#pragma unroll
  for (int i = 0; i < 32; ++i) acc[i] = 0.f;
#pragma unroll
  for (int c = 0; c < 4; ++c) {
    if (c < nch) {
      const char* p = pb + (size_t)c * SLOT_BYTES;
      l += ((const float*)(p + 16384))[q];
      const short* o = (const short*)p + q * 64 + dc;
#pragma unroll
      for (int blk = 0; blk < 4; ++blk) {
        short8 r = *(const short8*)(o + blk * 8);
#pragma unroll
        for (int i = 0; i < 8; ++i) acc[blk * 8 + i] += bits2f((ushort_t)r[i]);
      }
    }
  }
  const float inv = 1.0f / l;
  __align__(16) short out[32];
#pragma unroll
  for (int i = 0; i < 16; ++i)
    ((uint_t*)out)[i] = pack2bf_rn(acc[2 * i] * inv, acc[2 * i + 1] * inv);
  short* dst = (short*)abuf + (size_t)(b * LL + qt * 128 + q) * EE + h * DD + dc;
#pragma unroll
  for (int blk = 0; blk < 4; ++blk)
    *(short8*)(dst + blk * 8) = *(short8*)(out + blk * 8);
}

extern "C" void kernel_launch(void* const* d_in, const int* in_sizes, int n_in,
                              void* d_out, int out_size, void* d_ws, size_t ws_size,
                              hipStream_t stream) {
  (void)in_sizes; (void)n_in; (void)out_size; (void)ws_size;
  const float* x     = (const float*)d_in[0];
  const float* w_in  = (const float*)d_in[1];
  const float* b_in  = (const float*)d_in[2];
  const float* A_in  = (const float*)d_in[3];
  const float* B_in  = (const float*)d_in[4];
  const float* w_out = (const float*)d_in[5];
  const float* b_out = (const float*)d_in[6];
  const float* A_out = (const float*)d_in[7];
  const float* B_out = (const float*)d_in[8];
  char* ws = (char*)d_ws;
  __hip_bfloat16* xb   = (__hip_bfloat16*)(ws);
  __hip_bfloat16* w1T  = (__hip_bfloat16*)(ws + 6291456);
  __hip_bfloat16* w2T  = (__hip_bfloat16*)(ws + 9830400);
  __hip_bfloat16* qkv  = (__hip_bfloat16*)(ws + 11010048);
  __hip_bfloat16* vT   = (__hip_bfloat16*)(ws + 29884416);
  __hip_bfloat16* abuf = (__hip_bfloat16*)(ws + 36175872);
  char* Opart          = ws + 42467328;   // 24*16*4 slots x 16896 B = 25.9 MB

  prep_kernel<<<3072, 256, 0, stream>>>(x, w_in, A_in, B_in, w_out, A_out, B_out,
                                        xb, w1T, w2T);
  gemm_bt<false, true, true><<<dim3(N3 / 128, TOK / 128), 256, 0, stream>>>(
      xb, w1T, b_in, qkv, vT, TOK, N3, EE);
  attn_kernel<<<24 * 40, 256, 0, stream>>>(qkv, vT, Opart, abuf);
  merge_kernel<<<24 * 12, 256, 0, stream>>>(Opart, abuf);
  gemm_bt<true, false, false><<<dim3(EE / 128, TOK / 128), 256, 0, stream>>>(
      abuf, w2T, b_out, d_out, nullptr, TOK, EE, EE);
}

// Round 7
// 157.215 us; speedup vs baseline: 1.3186x; 1.3186x over previous
//
#include <hip/hip_runtime.h>
#include <hip/hip_bf16.h>

#define BB 2
#define LL 2048
#define EE 768
#define HH 12
#define DD 64
#define N3 2304
#define TOK 4096   // BB*LL
#define LOG2E 1.4426950408889634f

typedef __attribute__((ext_vector_type(8))) short short8;
typedef __attribute__((ext_vector_type(4))) short s16x4;
typedef __attribute__((ext_vector_type(4))) float f32x4;
typedef __attribute__((ext_vector_type(4))) unsigned int uix4;
typedef unsigned int uint_t;
typedef unsigned short ushort_t;

__device__ __forceinline__ f32x4 mfma16(short8 a, short8 b, f32x4 c) {
  return __builtin_amdgcn_mfma_f32_16x16x32_bf16(a, b, c, 0, 0, 0);
}
// K=16 bf16 MFMA: B-layout B[k=quad*4+j][n=c16] == S^T C-layout -> P is a
// zero-cost B operand.
__device__ __forceinline__ f32x4 mfma16k16(s16x4 a, s16x4 b, f32x4 c) {
  return __builtin_amdgcn_mfma_f32_16x16x16bf16_1k(a, b, c, 0, 0, 0);
}

__device__ __forceinline__ ushort_t bf16bits(float f) {
  __hip_bfloat16 h = __float2bfloat16(f);
  return *reinterpret_cast<ushort_t*>(&h);
}

// raw v_exp_f32 (base-2 exp), avoids OCML multi-instruction expansion
__device__ __forceinline__ float fast_exp2(float x) {
  float r;
  asm("v_exp_f32 %0, %1" : "=v"(r) : "v"(x));
  return r;
}

// cheap bf16 pair pack: round-half-up via +0x8000, truncate
__device__ __forceinline__ uint_t pack2bf_rn(float a, float b) {
  uint_t ua = __float_as_uint(a) + 0x8000u;
  uint_t ub = __float_as_uint(b) + 0x8000u;
  return (ua >> 16) | (ub & 0xFFFF0000u);
}

__device__ __forceinline__ float bits2f(ushort_t u) {
  union { uint_t u; float f; } cv;
  cv.u = ((uint_t)u) << 16;
  return cv.f;
}

// ---- global -> LDS staging, XOR-swizzled 16B chunks ----------------------
// 128 rows x 64 bf16 (16 KB) — used by the GEMMs.
__device__ __forceinline__ void stage64(const __hip_bfloat16* gbase, int ldg,
                                        short* lds, int tid) {
  const int wave = tid >> 6, lane = tid & 63;
#pragma unroll
  for (int c = 0; c < 4; ++c) {
    int off = c * 4096 + wave * 1024 + lane * 16;   // byte offset in tile
    int row = off >> 7;
    int cs  = (off & 127) >> 4;
    int cc  = cs ^ (row & 7);
    __builtin_amdgcn_global_load_lds(
        (const __attribute__((address_space(1))) void*)((const short*)gbase + (size_t)row * ldg + cc * 8),
        (__attribute__((address_space(3))) void*)(lds + c * 2048 + wave * 512),
        16, 0, 0);
  }
}

// 64 rows x 64 bf16 (8 KB) — attn K and V^T tiles.
__device__ __forceinline__ void stage64h(const __hip_bfloat16* gbase, int ldg,
                                         short* lds, int tid) {
  const int wave = tid >> 6, lane = tid & 63;
#pragma unroll
  for (int c = 0; c < 2; ++c) {
    int off = c * 4096 + wave * 1024 + lane * 16;
    int row = off >> 7;
    int cs  = (off & 127) >> 4;
    int cc  = cs ^ (row & 7);
    __builtin_amdgcn_global_load_lds(
        (const __attribute__((address_space(1))) void*)((const short*)gbase + (size_t)row * ldg + cc * 8),
        (__attribute__((address_space(3))) void*)(lds + c * 2048 + wave * 512),
        16, 0, 0);
  }
}

__device__ __forceinline__ short8 frag64(const short* lds, int row, int chunk) {
  return *(const short8*)(lds + row * 64 + (chunk ^ (row & 7)) * 8);
}

// ---- prep: LDS-tiled transpose + LoRA fold -> w1T/w2T; coalesced x cast --
__global__ void prep_kernel(const float* __restrict__ x, const float* __restrict__ w_in,
                            const float* __restrict__ A_in, const float* __restrict__ B_in,
                            const float* __restrict__ w_out, const float* __restrict__ A_out,
                            const float* __restrict__ B_out,
                            __hip_bfloat16* __restrict__ xb, __hip_bfloat16* __restrict__ w1T,
                            __hip_bfloat16* __restrict__ w2T) {
  __shared__ float tile[32][33];
  const int bid = blockIdx.x, t = threadIdx.x;
  if (bid < 2304) {
    const float *W, *Am, *Bm;
    __hip_bfloat16* out;
    int N, tx, ty;
    if (bid < 1728) { W = w_in;  Am = A_in;  Bm = B_in;  out = w1T; N = N3; tx = bid % 72; ty = bid / 72; }
    else { int jj = bid - 1728; W = w_out; Am = A_out; Bm = B_out; out = w2T; N = EE; tx = jj % 24; ty = jj / 24; }
    const int e0 = ty * 32, o0 = tx * 32;
    const int r = t >> 5, col = t & 31;
#pragma unroll
    for (int i = 0; i < 4; ++i)
      tile[r + i * 8][col] = W[(size_t)(e0 + r + i * 8) * N + (o0 + col)];
    __syncthreads();
    const int e = e0 + col;
    const float b0 = Bm[e * 4 + 0], b1 = Bm[e * 4 + 1], b2 = Bm[e * 4 + 2], b3 = Bm[e * 4 + 3];
#pragma unroll
    for (int i = 0; i < 4; ++i) {
      const int o = o0 + r + i * 8;
      float acc = b0 * Am[o] + b1 * Am[N + o] + b2 * Am[2 * N + o] + b3 * Am[3 * N + o];
      out[(size_t)o * EE + e] = __float2bfloat16(tile[col][r + i * 8] + 8.0f * acc);
    }
  } else {
    const int j = bid - 2304;              // 768 blocks x 4096 f32 each
    const float* src = x + (size_t)j * 4096 + t * 16;
    short* dst = (short*)xb + (size_t)j * 4096 + t * 16;
#pragma unroll
    for (int half = 0; half < 2; ++half) {
      float4 a = ((const float4*)src)[half * 2];
      float4 b = ((const float4*)src)[half * 2 + 1];
      short8 v;
      v[0] = (short)bf16bits(a.x); v[1] = (short)bf16bits(a.y);
      v[2] = (short)bf16bits(a.z); v[3] = (short)bf16bits(a.w);
      v[4] = (short)bf16bits(b.x); v[5] = (short)bf16bits(b.y);
      v[6] = (short)bf16bits(b.z); v[7] = (short)bf16bits(b.w);
      ((short8*)dst)[half] = v;
    }
  }
}

// ---- GEMM: C[M,N] = A[M,K] @ BT[N,K]^T + bias, 128x128 tile, BK=64 -------
// QSCALE: scale cols n<EE by log2e. SPLITV: cols n>=2E are written
// TRANSPOSED into vT[b*768 + (n-2E)][l] instead of row-major outp.
template<bool F32OUT, bool QSCALE, bool SPLITV>
__global__ __launch_bounds__(256, 2) void gemm_bt(const __hip_bfloat16* __restrict__ A,
                                                  const __hip_bfloat16* __restrict__ BT,
                                                  const float* __restrict__ bias,
                                                  void* __restrict__ outp,
                                                  __hip_bfloat16* __restrict__ vTp,
                                                  int M, int N, int K) {
  __shared__ __align__(16) short Al[128 * 64];
  __shared__ __align__(16) short Bl[128 * 64];
  const int tid = threadIdx.x, lane = tid & 63, wave = tid >> 6;
  const int quad = lane >> 4, c16 = lane & 15;
  const int n0 = blockIdx.x * 128, m0 = blockIdx.y * 128;
  const int msub = (wave & 1) * 64, nsub = (wave >> 1) * 64;
  f32x4 acc[4][4] = {};
  for (int k0 = 0; k0 < K; k0 += 64) {
    __syncthreads();
    stage64(A + (size_t)m0 * K + k0, K, Al, tid);
    stage64(BT + (size_t)n0 * K + k0, K, Bl, tid);
    __syncthreads();
#pragma unroll
    for (int ks = 0; ks < 2; ++ks) {
      short8 af[4], bfr[4];
#pragma unroll
      for (int i = 0; i < 4; ++i) {
        af[i]  = frag64(Al, msub + i * 16 + c16, ks * 4 + quad);
        bfr[i] = frag64(Bl, nsub + i * 16 + c16, ks * 4 + quad);
      }
#pragma unroll
      for (int mi = 0; mi < 4; ++mi)
#pragma unroll
        for (int ni = 0; ni < 4; ++ni)
          acc[mi][ni] = mfma16(af[mi], bfr[ni], acc[mi][ni]);
    }
  }
  if (SPLITV && n0 >= 2 * EE) {          // V block: transposed scatter to vT
    const int bofs = (m0 >> 11) * EE;    // b*768
    const int l0 = (m0 & 2047) + msub;
#pragma unroll
    for (int ni = 0; ni < 4; ++ni) {
      int n = n0 + nsub + ni * 16 + c16;
      float bv = bias[n];
      const size_t rowbase = (size_t)(bofs + (n - 2 * EE)) * LL;
#pragma unroll
      for (int mi = 0; mi < 4; ++mi) {
        int l = l0 + mi * 16 + quad * 4;
        uint2 w;
        w.x = pack2bf_rn(acc[mi][ni][0] + bv, acc[mi][ni][1] + bv);
        w.y = pack2bf_rn(acc[mi][ni][2] + bv, acc[mi][ni][3] + bv);
        *(uint2*)((short*)vTp + rowbase + l) = w;
      }
    }
    return;
  }
#pragma unroll
  for (int ni = 0; ni < 4; ++ni) {
    int n = n0 + nsub + ni * 16 + c16;
    float bv = bias[n];
    float sc = (QSCALE && n < EE) ? LOG2E : 1.0f;
#pragma unroll
    for (int mi = 0; mi < 4; ++mi) {
      int row0 = m0 + msub + mi * 16 + quad * 4;
#pragma unroll
      for (int r = 0; r < 4; ++r) {
        float v = (acc[mi][ni][r] + bv) * sc;
        if (F32OUT) ((float*)outp)[(size_t)(row0 + r) * N + n] = v;
        else ((__hip_bfloat16*)outp)[(size_t)(row0 + r) * N + n] = __float2bfloat16(v);
      }
    }
  }
}

// ---- split-K flash attention, fixed-max softmax ---------------------------
// Block = (b,h, 128-q tile, 512-token chunk), 40 slots/bh heavy-first, 960
// blocks all co-resident. Double-buffered 64-k LDS tiles (32 KB total) ->
// 4-5 blocks/CU interleave independent barrier pipelines. qt<4 writes
// normalized output straight to abuf; others write partials to Opart.
#define SLOT_BYTES 16896   // 128*64*2 (O) + 128*4 (l)
union pk4 { uint_t u[2]; s16x4 s4; };

__device__ const signed char QTAB[40] = {
  3,4,5,6,7,8,9,10,11,12,13,14,15,  7,8,9,10,11,12,13,14,15,
  11,12,13,14,15, 15,  2,6,10,14,  1,5,9,13,  0,4,8,12};
__device__ const signed char CTAB[40] = {
  0,0,0,0,0,0,0,0,0,0,0,0,0,  1,1,1,1,1,1,1,1,1,
  2,2,2,2,2, 3,  0,1,2,3,  0,1,2,3,  0,1,2,3};

__global__ __launch_bounds__(256, 4) void attn_kernel(const __hip_bfloat16* __restrict__ qkv,
                                                      const __hip_bfloat16* __restrict__ vT,
                                                      char* __restrict__ Opart,
                                                      __hip_bfloat16* __restrict__ abuf) {
  __shared__ __align__(16) short Kl[2 * 64 * 64];   // 16 KB dbuf
  __shared__ __align__(16) short Vl[2 * 64 * 64];   // 16 KB dbuf
  const int tid = threadIdx.x, lane = tid & 63, wave = tid >> 6;
  const int quad = lane >> 4, c16 = lane & 15;
  const int bid = blockIdx.x;
  const int bh = bid % 24;
  const int j = bid / 24;
  const int qt = QTAB[j], cch = CTAB[j];
  const int b = bh / HH, h = bh % HH;
  const int q0 = qt * 128;
  const int qw = q0 + wave * 32;        // wave's first q row (A half)
  const int ks = cch * 512;
  const int ke = min(q0 + 128, ks + 512);
  const int niter = (ke - ks + 63) >> 6;
  short8 qfA[2], qfB[2];
  {
    const short* qra = (const short*)qkv + (size_t)(b * LL + qw + c16) * N3 + h * DD;
    qfA[0] = *(const short8*)(qra + quad * 8);
    qfA[1] = *(const short8*)(qra + 32 + quad * 8);
    const short* qrb = qra + 16 * N3;
    qfB[0] = *(const short8*)(qrb + quad * 8);
    qfB[1] = *(const short8*)(qrb + 32 + quad * 8);
  }
  float lA = 0.f, lB = 0.f;
  f32x4 oA[4] = {}, oB[4] = {};         // O^T: d = dt*16+quad*4+r, q = c16
  const int vsub = (quad & 1) * 4;
  const int cxor = (c16 & 7);
  const __hip_bfloat16* kgbase = qkv + (size_t)(b * LL) * N3 + EE + h * DD;
  const __hip_bfloat16* vgbase = vT + (size_t)((b * HH + h) * DD) * LL;
  // prologue stage into buf 0
  stage64h(kgbase + (size_t)ks * N3, N3, Kl, tid);
  stage64h(vgbase + ks, LL, Vl, tid);
  for (int it = 0; it < niter; ++it) {
    const int k0 = ks + it * 64;
    __syncthreads();                    // drains prev stage; frees other buf
    if (it + 1 < niter) {               // prefetch next 64-k tile -> alt buf
      short* Kn = Kl + ((it + 1) & 1) * 4096;
      short* Vn = Vl + ((it + 1) & 1) * 4096;
      stage64h(kgbase + (size_t)(k0 + 64) * N3, N3, Kn, tid);
      stage64h(vgbase + k0 + 64, LL, Vn, tid);
    }
    const short* Kb = Kl + (it & 1) * 4096;
    const short* Vb = Vl + (it & 1) * 4096;
    int nlimB = (qw + 31 - k0) / 16 + 1; if (nlimB > 4) nlimB = 4;
    int nlimA = (qw + 15 - k0) / 16 + 1; if (nlimA > 4) nlimA = 4;
#pragma unroll
    for (int nt = 0; nt < 4; ++nt) {
      if (nt < nlimB) {
        const short* krow = Kb + (nt * 16 + c16) * 64;
        const int kc0 = (quad ^ cxor) * 8;
        short8 kf0 = *(const short8*)(krow + kc0);
        short8 kf1 = *(const short8*)(krow + (kc0 ^ 32));
        const int kb = k0 + nt * 16 + quad * 4;
        const bool diag = (k0 + nt * 16 + 15 > qw + 16);
        f32x4 sB = {};
        sB = mfma16(kf0, qfB[0], sB);
        sB = mfma16(kf1, qfB[1], sB);
        if (diag) {
          const int q = qw + 16 + c16;
#pragma unroll
          for (int r = 0; r < 4; ++r)
            if (kb + r > q) sB[r] = -1e9f;
        }
        pk4 pB;
        {
          float p0 = fast_exp2(sB[0]), p1 = fast_exp2(sB[1]);
          float p2 = fast_exp2(sB[2]), p3 = fast_exp2(sB[3]);
          lB += (p0 + p1) + (p2 + p3);
          pB.u[0] = pack2bf_rn(p0, p1);
          pB.u[1] = pack2bf_rn(p2, p3);
        }
        const bool doA = (nt < nlimA);
        pk4 pA;
        if (doA) {
          f32x4 sA = {};
          sA = mfma16(kf0, qfA[0], sA);
          sA = mfma16(kf1, qfA[1], sA);
          if (k0 + nt * 16 + 15 > qw) {
            const int q = qw + c16;
#pragma unroll
            for (int r = 0; r < 4; ++r)
              if (kb + r > q) sA[r] = -1e9f;
          }
          float p0 = fast_exp2(sA[0]), p1 = fast_exp2(sA[1]);
          float p2 = fast_exp2(sA[2]), p3 = fast_exp2(sA[3]);
          lA += (p0 + p1) + (p2 + p3);
          pA.u[0] = pack2bf_rn(p0, p1);
          pA.u[1] = pack2bf_rn(p2, p3);
        }
        // PV: A-frag = V^T[d=dt*16+c16][k0+nt*16+quad*4 ..+3] b64 LDS reads
        const int cg = (nt * 2 + (quad >> 1)) ^ cxor;
        const short* vbase = Vb + c16 * 64 + cg * 8 + vsub;
#pragma unroll
        for (int dt = 0; dt < 4; ++dt) {
          s16x4 vf = *(const s16x4*)(vbase + dt * 1024);
          oB[dt] = mfma16k16(vf, pB.s4, oB[dt]);
          if (doA) oA[dt] = mfma16k16(vf, pA.s4, oA[dt]);
        }
      }
    }
  }
  lA += __shfl_xor(lA, 16); lA += __shfl_xor(lA, 32);
  lB += __shfl_xor(lB, 16); lB += __shfl_xor(lB, 32);
  const bool single = (cch == 0) && (qt < 4);
  const float nA = single ? 1.0f / lA : 1.0f;
  const float nB = single ? 1.0f / lB : 1.0f;
  char* op = Opart + (size_t)((bh * 16 + qt) * 4 + cch) * SLOT_BYTES;
  if (!single && quad == 0) {
    float* lout = (float*)(op + 16384);
    lout[wave * 32 + c16] = lA;
    lout[wave * 32 + 16 + c16] = lB;
  }
  __syncthreads();                      // all waves done reading K/V LDS
  short* reg = Kl + wave * 1152;        // 16 q x 72-short rows (private)
#pragma unroll
  for (int hh = 0; hh < 2; ++hh) {
    const float sc = hh ? nB : nA;
#pragma unroll
    for (int dt = 0; dt < 4; ++dt) {
      f32x4 o = hh ? oB[dt] : oA[dt];
      uint_t* p = (uint_t*)(reg + c16 * 72 + dt * 16 + quad * 4);
      p[0] = pack2bf_rn(o[0] * sc, o[1] * sc);
      p[1] = pack2bf_rn(o[2] * sc, o[3] * sc);
    }
#pragma unroll
    for (int it = 0; it < 2; ++it) {
      int idx = it * 64 + lane;
      int tq = idx >> 3, c = idx & 7;
      short8 v = *(const short8*)(reg + tq * 72 + c * 8);
      if (single)
        *(short8*)((short*)abuf + (size_t)(b * LL + q0 + wave * 32 + hh * 16 + tq) * EE + h * DD + c * 8) = v;
      else
        *(short8*)((short*)op + (wave * 32 + hh * 16 + tq) * 64 + c * 8) = v;
    }
  }
}

// ---- merge (qt>=4): sum nch=qt/4+1 partials, normalize, write abuf -------
__global__ void merge_kernel(const char* __restrict__ Opart,
                             __hip_bfloat16* __restrict__ abuf) {
  const int t = threadIdx.x;
  const int bh = blockIdx.x / 12, qt = 4 + (blockIdx.x % 12);
  const int nch = (qt >> 2) + 1;
  const int b = bh / HH, h = bh % HH;
  const char* pb = Opart + (size_t)((bh * 16 + qt) * 4) * SLOT_BYTES;
  const int q = t >> 1, dc = (t & 1) * 32;
  float l = 0.f;
  float acc[32];
#pragma unroll
  for (int i = 0; i < 32; ++i) acc[i] = 0.f;
#pragma unroll
  for (int c = 0; c < 4; ++c) {
    if (c < nch) {
      const char* p = pb + (size_t)c * SLOT_BYTES;
      l += ((const float*)(p + 16384))[q];
      const short* o = (const short*)p + q * 64 + dc;
#pragma unroll
      for (int blk = 0; blk < 4; ++blk) {
        short8 r = *(const short8*)(o + blk * 8);
#pragma unroll
        for (int i = 0; i < 8; ++i) acc[blk * 8 + i] += bits2f((ushort_t)r[i]);
      }
    }
  }
  const float inv = 1.0f / l;
  __align__(16) short out[32];
#pragma unroll
  for (int i = 0; i < 16; ++i)
    ((uint_t*)out)[i] = pack2bf_rn(acc[2 * i] * inv, acc[2 * i + 1] * inv);
  short* dst = (short*)abuf + (size_t)(b * LL + qt * 128 + q) * EE + h * DD + dc;
#pragma unroll
  for (int blk = 0; blk < 4; ++blk)
    *(short8*)(dst + blk * 8) = *(short8*)(out + blk * 8);
}

extern "C" void kernel_launch(void* const* d_in, const int* in_sizes, int n_in,
                              void* d_out, int out_size, void* d_ws, size_t ws_size,
                              hipStream_t stream) {
  (void)in_sizes; (void)n_in; (void)out_size; (void)ws_size;
  const float* x     = (const float*)d_in[0];
  const float* w_in  = (const float*)d_in[1];
  const float* b_in  = (const float*)d_in[2];
  const float* A_in  = (const float*)d_in[3];
  const float* B_in  = (const float*)d_in[4];
  const float* w_out = (const float*)d_in[5];
  const float* b_out = (const float*)d_in[6];
  const float* A_out = (const float*)d_in[7];
  const float* B_out = (const float*)d_in[8];
  char* ws = (char*)d_ws;
  __hip_bfloat16* xb   = (__hip_bfloat16*)(ws);
  __hip_bfloat16* w1T  = (__hip_bfloat16*)(ws + 6291456);
  __hip_bfloat16* w2T  = (__hip_bfloat16*)(ws + 9830400);
  __hip_bfloat16* qkv  = (__hip_bfloat16*)(ws + 11010048);
  __hip_bfloat16* vT   = (__hip_bfloat16*)(ws + 29884416);
  __hip_bfloat16* abuf = (__hip_bfloat16*)(ws + 36175872);
  char* Opart          = ws + 42467328;   // 24*16*4 slots x 16896 B = 25.9 MB

  prep_kernel<<<3072, 256, 0, stream>>>(x, w_in, A_in, B_in, w_out, A_out, B_out,
                                        xb, w1T, w2T);
  gemm_bt<false, true, true><<<dim3(N3 / 128, TOK / 128), 256, 0, stream>>>(
      xb, w1T, b_in, qkv, vT, TOK, N3, EE);
  attn_kernel<<<24 * 40, 256, 0, stream>>>(qkv, vT, Opart, abuf);
  merge_kernel<<<24 * 12, 256, 0, stream>>>(Opart, abuf);
  gemm_bt<true, false, false><<<dim3(EE / 128, TOK / 128), 256, 0, stream>>>(
      abuf, w2T, b_out, d_out, nullptr, TOK, EE, EE);
}

// Round 8
// 156.092 us; speedup vs baseline: 1.3281x; 1.0072x over previous
//
#include <hip/hip_runtime.h>
#include <hip/hip_bf16.h>

#define BB 2
#define LL 2048
#define EE 768
#define HH 12
#define DD 64
#define N3 2304
#define TOK 4096   // BB*LL
#define LOG2E 1.4426950408889634f

typedef __attribute__((ext_vector_type(8))) short short8;
typedef __attribute__((ext_vector_type(4))) short s16x4;
typedef __attribute__((ext_vector_type(4))) float f32x4;
typedef __attribute__((ext_vector_type(4))) unsigned int uix4;
typedef unsigned int uint_t;
typedef unsigned short ushort_t;

__device__ __forceinline__ f32x4 mfma16(short8 a, short8 b, f32x4 c) {
  return __builtin_amdgcn_mfma_f32_16x16x32_bf16(a, b, c, 0, 0, 0);
}
// K=16 bf16 MFMA: B-layout B[k=quad*4+j][n=c16] == S^T C-layout -> P is a
// zero-cost B operand.
__device__ __forceinline__ f32x4 mfma16k16(s16x4 a, s16x4 b, f32x4 c) {
  return __builtin_amdgcn_mfma_f32_16x16x16bf16_1k(a, b, c, 0, 0, 0);
}

__device__ __forceinline__ ushort_t bf16bits(float f) {
  __hip_bfloat16 h = __float2bfloat16(f);
  return *reinterpret_cast<ushort_t*>(&h);
}

// raw v_exp_f32 (base-2 exp), avoids OCML multi-instruction expansion
__device__ __forceinline__ float fast_exp2(float x) {
  float r;
  asm("v_exp_f32 %0, %1" : "=v"(r) : "v"(x));
  return r;
}

// cheap bf16 pair pack: round-half-up via +0x8000, truncate
__device__ __forceinline__ uint_t pack2bf_rn(float a, float b) {
  uint_t ua = __float_as_uint(a) + 0x8000u;
  uint_t ub = __float_as_uint(b) + 0x8000u;
  return (ua >> 16) | (ub & 0xFFFF0000u);
}

__device__ __forceinline__ float bits2f(ushort_t u) {
  union { uint_t u; float f; } cv;
  cv.u = ((uint_t)u) << 16;
  return cv.f;
}

// ---- global -> LDS staging, XOR-swizzled 16B chunks ----------------------
// 128 rows x 64 bf16 (16 KB).
__device__ __forceinline__ void stage64(const __hip_bfloat16* gbase, int ldg,
                                        short* lds, int tid) {
  const int wave = tid >> 6, lane = tid & 63;
#pragma unroll
  for (int c = 0; c < 4; ++c) {
    int off = c * 4096 + wave * 1024 + lane * 16;   // byte offset in tile
    int row = off >> 7;
    int cs  = (off & 127) >> 4;
    int cc  = cs ^ (row & 7);
    __builtin_amdgcn_global_load_lds(
        (const __attribute__((address_space(1))) void*)((const short*)gbase + (size_t)row * ldg + cc * 8),
        (__attribute__((address_space(3))) void*)(lds + c * 2048 + wave * 512),
        16, 0, 0);
  }
}

// 64 rows x 64 bf16 (8 KB).
__device__ __forceinline__ void stage64h(const __hip_bfloat16* gbase, int ldg,
                                         short* lds, int tid) {
  const int wave = tid >> 6, lane = tid & 63;
#pragma unroll
  for (int c = 0; c < 2; ++c) {
    int off = c * 4096 + wave * 1024 + lane * 16;
    int row = off >> 7;
    int cs  = (off & 127) >> 4;
    int cc  = cs ^ (row & 7);
    __builtin_amdgcn_global_load_lds(
        (const __attribute__((address_space(1))) void*)((const short*)gbase + (size_t)row * ldg + cc * 8),
        (__attribute__((address_space(3))) void*)(lds + c * 2048 + wave * 512),
        16, 0, 0);
  }
}

__device__ __forceinline__ short8 frag64(const short* lds, int row, int chunk) {
  return *(const short8*)(lds + row * 64 + (chunk ^ (row & 7)) * 8);
}

// ---- prep: LDS-tiled transpose + LoRA fold -> w1T/w2T; coalesced x cast --
__global__ void prep_kernel(const float* __restrict__ x, const float* __restrict__ w_in,
                            const float* __restrict__ A_in, const float* __restrict__ B_in,
                            const float* __restrict__ w_out, const float* __restrict__ A_out,
                            const float* __restrict__ B_out,
                            __hip_bfloat16* __restrict__ xb, __hip_bfloat16* __restrict__ w1T,
                            __hip_bfloat16* __restrict__ w2T) {
  __shared__ float tile[32][33];
  const int bid = blockIdx.x, t = threadIdx.x;
  if (bid < 2304) {
    const float *W, *Am, *Bm;
    __hip_bfloat16* out;
    int N, tx, ty;
    if (bid < 1728) { W = w_in;  Am = A_in;  Bm = B_in;  out = w1T; N = N3; tx = bid % 72; ty = bid / 72; }
    else { int jj = bid - 1728; W = w_out; Am = A_out; Bm = B_out; out = w2T; N = EE; tx = jj % 24; ty = jj / 24; }
    const int e0 = ty * 32, o0 = tx * 32;
    const int r = t >> 5, col = t & 31;
#pragma unroll
    for (int i = 0; i < 4; ++i)
      tile[r + i * 8][col] = W[(size_t)(e0 + r + i * 8) * N + (o0 + col)];
    __syncthreads();
    const int e = e0 + col;
    const float b0 = Bm[e * 4 + 0], b1 = Bm[e * 4 + 1], b2 = Bm[e * 4 + 2], b3 = Bm[e * 4 + 3];
#pragma unroll
    for (int i = 0; i < 4; ++i) {
      const int o = o0 + r + i * 8;
      float acc = b0 * Am[o] + b1 * Am[N + o] + b2 * Am[2 * N + o] + b3 * Am[3 * N + o];
      out[(size_t)o * EE + e] = __float2bfloat16(tile[col][r + i * 8] + 8.0f * acc);
    }
  } else {
    const int j = bid - 2304;              // 768 blocks x 4096 f32 each
    const float* src = x + (size_t)j * 4096 + t * 16;
    short* dst = (short*)xb + (size_t)j * 4096 + t * 16;
#pragma unroll
    for (int half = 0; half < 2; ++half) {
      float4 a = ((const float4*)src)[half * 2];
      float4 b = ((const float4*)src)[half * 2 + 1];
      short8 v;
      v[0] = (short)bf16bits(a.x); v[1] = (short)bf16bits(a.y);
      v[2] = (short)bf16bits(a.z); v[3] = (short)bf16bits(a.w);
      v[4] = (short)bf16bits(b.x); v[5] = (short)bf16bits(b.y);
      v[6] = (short)bf16bits(b.z); v[7] = (short)bf16bits(b.w);
      ((short8*)dst)[half] = v;
    }
  }
}

// ---- GEMM: C[M,N] = A[M,K] @ BT[N,K]^T + bias, (128 x NT) tile, BK=64 ----
// NT in {128,64}. QSCALE: scale cols n<EE by log2e. SPLITV: cols n>=2E are
// written TRANSPOSED into vT[b*768 + (n-2E)][l] instead of row-major outp.
template<int NT, bool F32OUT, bool QSCALE, bool SPLITV>
__global__ __launch_bounds__(256, 3) void gemm_bt(const __hip_bfloat16* __restrict__ A,
                                                  const __hip_bfloat16* __restrict__ BT,
                                                  const float* __restrict__ bias,
                                                  void* __restrict__ outp,
                                                  __hip_bfloat16* __restrict__ vTp,
                                                  int M, int N, int K) {
  constexpr int NACC = NT / 32;          // ni-fragments per wave
  __shared__ __align__(16) short Al[128 * 64];
  __shared__ __align__(16) short Bl[NT * 64];
  const int tid = threadIdx.x, lane = tid & 63, wave = tid >> 6;
  const int quad = lane >> 4, c16 = lane & 15;
  const int n0 = blockIdx.x * NT, m0 = blockIdx.y * 128;
  const int msub = (wave & 1) * 64, nsub = (wave >> 1) * (NT / 2);
  f32x4 acc[4][NACC] = {};
  for (int k0 = 0; k0 < K; k0 += 64) {
    __syncthreads();
    stage64(A + (size_t)m0 * K + k0, K, Al, tid);
    if (NT == 128) stage64(BT + (size_t)n0 * K + k0, K, Bl, tid);
    else           stage64h(BT + (size_t)n0 * K + k0, K, Bl, tid);
    __syncthreads();
#pragma unroll
    for (int ks = 0; ks < 2; ++ks) {
      short8 af[4], bfr[NACC];
#pragma unroll
      for (int i = 0; i < 4; ++i)
        af[i] = frag64(Al, msub + i * 16 + c16, ks * 4 + quad);
#pragma unroll
      for (int i = 0; i < NACC; ++i)
        bfr[i] = frag64(Bl, nsub + i * 16 + c16, ks * 4 + quad);
#pragma unroll
      for (int mi = 0; mi < 4; ++mi)
#pragma unroll
        for (int ni = 0; ni < NACC; ++ni)
          acc[mi][ni] = mfma16(af[mi], bfr[ni], acc[mi][ni]);
    }
  }
  if (SPLITV && n0 >= 2 * EE) {          // V block: transposed scatter to vT
    const int bofs = (m0 >> 11) * EE;    // b*768
    const int l0 = (m0 & 2047) + msub;
#pragma unroll
    for (int ni = 0; ni < NACC; ++ni) {
      int n = n0 + nsub + ni * 16 + c16;
      float bv = bias[n];
      const size_t rowbase = (size_t)(bofs + (n - 2 * EE)) * LL;
#pragma unroll
      for (int mi = 0; mi < 4; ++mi) {
        int l = l0 + mi * 16 + quad * 4;
        uint2 w;
        w.x = pack2bf_rn(acc[mi][ni][0] + bv, acc[mi][ni][1] + bv);
        w.y = pack2bf_rn(acc[mi][ni][2] + bv, acc[mi][ni][3] + bv);
        *(uint2*)((short*)vTp + rowbase + l) = w;
      }
    }
    return;
  }
#pragma unroll
  for (int ni = 0; ni < NACC; ++ni) {
    int n = n0 + nsub + ni * 16 + c16;
    float bv = bias[n];
    float sc = (QSCALE && n < EE) ? LOG2E : 1.0f;
#pragma unroll
    for (int mi = 0; mi < 4; ++mi) {
      int row0 = m0 + msub + mi * 16 + quad * 4;
#pragma unroll
      for (int r = 0; r < 4; ++r) {
        float v = (acc[mi][ni][r] + bv) * sc;
        if (F32OUT) ((float*)outp)[(size_t)(row0 + r) * N + n] = v;
        else ((__hip_bfloat16*)outp)[(size_t)(row0 + r) * N + n] = __float2bfloat16(v);
      }
    }
  }
}

// ---- split-K flash attention, fixed-max softmax ---------------------------
// Block = (b,h, 128-q tile, 512-token chunk), 40 slots/bh heavy-first, 960
// blocks all co-resident. Double-buffered 64-k LDS tiles (32 KB total).
// qt<4 writes normalized output straight to abuf; others -> Opart partials.
#define SLOT_BYTES 16896   // 128*64*2 (O) + 128*4 (l)
union pk4 { uint_t u[2]; s16x4 s4; };

__device__ const signed char QTAB[40] = {
  3,4,5,6,7,8,9,10,11,12,13,14,15,  7,8,9,10,11,12,13,14,15,
  11,12,13,14,15, 15,  2,6,10,14,  1,5,9,13,  0,4,8,12};
__device__ const signed char CTAB[40] = {
  0,0,0,0,0,0,0,0,0,0,0,0,0,  1,1,1,1,1,1,1,1,1,
  2,2,2,2,2, 3,  0,1,2,3,  0,1,2,3,  0,1,2,3};

__global__ __launch_bounds__(256, 4) void attn_kernel(const __hip_bfloat16* __restrict__ qkv,
                                                      const __hip_bfloat16* __restrict__ vT,
                                                      char* __restrict__ Opart,
                                                      __hip_bfloat16* __restrict__ abuf) {
  __shared__ __align__(16) short Kl[2 * 64 * 64];   // 16 KB dbuf
  __shared__ __align__(16) short Vl[2 * 64 * 64];   // 16 KB dbuf
  const int tid = threadIdx.x, lane = tid & 63, wave = tid >> 6;
  const int quad = lane >> 4, c16 = lane & 15;
  const int bid = blockIdx.x;
  const int bh = bid % 24;
  const int j = bid / 24;
  const int qt = QTAB[j], cch = CTAB[j];
  const int b = bh / HH, h = bh % HH;
  const int q0 = qt * 128;
  const int qw = q0 + wave * 32;        // wave's first q row (A half)
  const int ks = cch * 512;
  const int ke = min(q0 + 128, ks + 512);
  const int niter = (ke - ks + 63) >> 6;
  short8 qfA[2], qfB[2];
  {
    const short* qra = (const short*)qkv + (size_t)(b * LL + qw + c16) * N3 + h * DD;
    qfA[0] = *(const short8*)(qra + quad * 8);
    qfA[1] = *(const short8*)(qra + 32 + quad * 8);
    const short* qrb = qra + 16 * N3;
    qfB[0] = *(const short8*)(qrb + quad * 8);
    qfB[1] = *(const short8*)(qrb + 32 + quad * 8);
  }
  float lA = 0.f, lB = 0.f;
  f32x4 oA[4] = {}, oB[4] = {};         // O^T: d = dt*16+quad*4+r, q = c16
  const int vsub = (quad & 1) * 4;
  const int cxor = (c16 & 7);
  const __hip_bfloat16* kgbase = qkv + (size_t)(b * LL) * N3 + EE + h * DD;
  const __hip_bfloat16* vgbase = vT + (size_t)((b * HH + h) * DD) * LL;
  // prologue stage into buf 0
  stage64h(kgbase + (size_t)ks * N3, N3, Kl, tid);
  stage64h(vgbase + ks, LL, Vl, tid);
  for (int it = 0; it < niter; ++it) {
    const int k0 = ks + it * 64;
    __syncthreads();                    // drains prev stage; frees other buf
    if (it + 1 < niter) {               // prefetch next 64-k tile -> alt buf
      short* Kn = Kl + ((it + 1) & 1) * 4096;
      short* Vn = Vl + ((it + 1) & 1) * 4096;
      stage64h(kgbase + (size_t)(k0 + 64) * N3, N3, Kn, tid);
      stage64h(vgbase + k0 + 64, LL, Vn, tid);
    }
    const short* Kb = Kl + (it & 1) * 4096;
    const short* Vb = Vl + (it & 1) * 4096;
    int nlimB = (qw + 31 - k0) / 16 + 1; if (nlimB > 4) nlimB = 4;
    int nlimA = (qw + 15 - k0) / 16 + 1; if (nlimA > 4) nlimA = 4;
#pragma unroll
    for (int nt = 0; nt < 4; ++nt) {
      if (nt < nlimB) {
        const short* krow = Kb + (nt * 16 + c16) * 64;
        const int kc0 = (quad ^ cxor) * 8;
        short8 kf0 = *(const short8*)(krow + kc0);
        short8 kf1 = *(const short8*)(krow + (kc0 ^ 32));
        const int kb = k0 + nt * 16 + quad * 4;
        const bool diag = (k0 + nt * 16 + 15 > qw + 16);
        f32x4 sB = {};
        sB = mfma16(kf0, qfB[0], sB);
        sB = mfma16(kf1, qfB[1], sB);
        if (diag) {
          const int q = qw + 16 + c16;
#pragma unroll
          for (int r = 0; r < 4; ++r)
            if (kb + r > q) sB[r] = -1e9f;
        }
        pk4 pB;
        {
          float p0 = fast_exp2(sB[0]), p1 = fast_exp2(sB[1]);
          float p2 = fast_exp2(sB[2]), p3 = fast_exp2(sB[3]);
          lB += (p0 + p1) + (p2 + p3);
          pB.u[0] = pack2bf_rn(p0, p1);
          pB.u[1] = pack2bf_rn(p2, p3);
        }
        const bool doA = (nt < nlimA);
        pk4 pA;
        if (doA) {
          f32x4 sA = {};
          sA = mfma16(kf0, qfA[0], sA);
          sA = mfma16(kf1, qfA[1], sA);
          if (k0 + nt * 16 + 15 > qw) {
            const int q = qw + c16;
#pragma unroll
            for (int r = 0; r < 4; ++r)
              if (kb + r > q) sA[r] = -1e9f;
          }
          float p0 = fast_exp2(sA[0]), p1 = fast_exp2(sA[1]);
          float p2 = fast_exp2(sA[2]), p3 = fast_exp2(sA[3]);
          lA += (p0 + p1) + (p2 + p3);
          pA.u[0] = pack2bf_rn(p0, p1);
          pA.u[1] = pack2bf_rn(p2, p3);
        }
        // PV: A-frag = V^T[d=dt*16+c16][k0+nt*16+quad*4 ..+3] b64 LDS reads
        const int cg = (nt * 2 + (quad >> 1)) ^ cxor;
        const short* vbase = Vb + c16 * 64 + cg * 8 + vsub;
#pragma unroll
        for (int dt = 0; dt < 4; ++dt) {
          s16x4 vf = *(const s16x4*)(vbase + dt * 1024);
          oB[dt] = mfma16k16(vf, pB.s4, oB[dt]);
          if (doA) oA[dt] = mfma16k16(vf, pA.s4, oA[dt]);
        }
      }
    }
  }
  lA += __shfl_xor(lA, 16); lA += __shfl_xor(lA, 32);
  lB += __shfl_xor(lB, 16); lB += __shfl_xor(lB, 32);
  const bool single = (cch == 0) && (qt < 4);
  const float nA = single ? 1.0f / lA : 1.0f;
  const float nB = single ? 1.0f / lB : 1.0f;
  char* op = Opart + (size_t)((bh * 16 + qt) * 4 + cch) * SLOT_BYTES;
  if (!single && quad == 0) {
    float* lout = (float*)(op + 16384);
    lout[wave * 32 + c16] = lA;
    lout[wave * 32 + 16 + c16] = lB;
  }
  __syncthreads();                      // all waves done reading K/V LDS
  short* reg = Kl + wave * 1152;        // 16 q x 72-short rows (private)
#pragma unroll
  for (int hh = 0; hh < 2; ++hh) {
    const float sc = hh ? nB : nA;
#pragma unroll
    for (int dt = 0; dt < 4; ++dt) {
      f32x4 o = hh ? oB[dt] : oA[dt];
      uint_t* p = (uint_t*)(reg + c16 * 72 + dt * 16 + quad * 4);
      p[0] = pack2bf_rn(o[0] * sc, o[1] * sc);
      p[1] = pack2bf_rn(o[2] * sc, o[3] * sc);
    }
#pragma unroll
    for (int it = 0; it < 2; ++it) {
      int idx = it * 64 + lane;
      int tq = idx >> 3, c = idx & 7;
      short8 v = *(const short8*)(reg + tq * 72 + c * 8);
      if (single)
        *(short8*)((short*)abuf + (size_t)(b * LL + q0 + wave * 32 + hh * 16 + tq) * EE + h * DD + c * 8) = v;
      else
        *(short8*)((short*)op + (wave * 32 + hh * 16 + tq) * 64 + c * 8) = v;
    }
  }
}

// ---- merge (qt>=4): sum nch=qt/4+1 partials, normalize, write abuf -------
__global__ void merge_kernel(const char* __restrict__ Opart,
                             __hip_bfloat16* __restrict__ abuf) {
  const int t = threadIdx.x;
  const int bh = blockIdx.x / 12, qt = 4 + (blockIdx.x % 12);
  const int nch = (qt >> 2) + 1;
  const int b = bh / HH, h = bh % HH;
  const char* pb = Opart + (size_t)((bh * 16 + qt) * 4) * SLOT_BYTES;
  const int q = t >> 1, dc = (t & 1) * 32;
  float l = 0.f;
  float acc[32];
#pragma unroll
  for (int i = 0; i < 32; ++i) acc[i] = 0.f;
#pragma unroll
  for (int c = 0; c < 4; ++c) {
    if (c < nch) {
      const char* p = pb + (size_t)c * SLOT_BYTES;
      l += ((const float*)(p + 16384))[q];
      const short* o = (const short*)p + q * 64 + dc;
#pragma unroll
      for (int blk = 0; blk < 4; ++blk) {
        short8 r = *(const short8*)(o + blk * 8);
#pragma unroll
        for (int i = 0; i < 8; ++i) acc[blk * 8 + i] += bits2f((ushort_t)r[i]);
      }
    }
  }
  const float inv = 1.0f / l;
  __align__(16) short out[32];
#pragma unroll
  for (int i = 0; i < 16; ++i)
    ((uint_t*)out)[i] = pack2bf_rn(acc[2 * i] * inv, acc[2 * i + 1] * inv);
  short* dst = (short*)abuf + (size_t)(b * LL + qt * 128 + q) * EE + h * DD + dc;
#pragma unroll
  for (int blk = 0; blk < 4; ++blk)
    *(short8*)(dst + blk * 8) = *(short8*)(out + blk * 8);
}

extern "C" void kernel_launch(void* const* d_in, const int* in_sizes, int n_in,
                              void* d_out, int out_size, void* d_ws, size_t ws_size,
                              hipStream_t stream) {
  (void)in_sizes; (void)n_in; (void)out_size; (void)ws_size;
  const float* x     = (const float*)d_in[0];
  const float* w_in  = (const float*)d_in[1];
  const float* b_in  = (const float*)d_in[2];
  const float* A_in  = (const float*)d_in[3];
  const float* B_in  = (const float*)d_in[4];
  const float* w_out = (const float*)d_in[5];
  const float* b_out = (const float*)d_in[6];
  const float* A_out = (const float*)d_in[7];
  const float* B_out = (const float*)d_in[8];
  char* ws = (char*)d_ws;
  __hip_bfloat16* xb   = (__hip_bfloat16*)(ws);
  __hip_bfloat16* w1T  = (__hip_bfloat16*)(ws + 6291456);
  __hip_bfloat16* w2T  = (__hip_bfloat16*)(ws + 9830400);
  __hip_bfloat16* qkv  = (__hip_bfloat16*)(ws + 11010048);
  __hip_bfloat16* vT   = (__hip_bfloat16*)(ws + 29884416);
  __hip_bfloat16* abuf = (__hip_bfloat16*)(ws + 36175872);
  char* Opart          = ws + 42467328;   // 24*16*4 slots x 16896 B = 25.9 MB

  prep_kernel<<<3072, 256, 0, stream>>>(x, w_in, A_in, B_in, w_out, A_out, B_out,
                                        xb, w1T, w2T);
  gemm_bt<128, false, true, true><<<dim3(N3 / 128, TOK / 128), 256, 0, stream>>>(
      xb, w1T, b_in, qkv, vT, TOK, N3, EE);
  attn_kernel<<<24 * 40, 256, 0, stream>>>(qkv, vT, Opart, abuf);
  merge_kernel<<<24 * 12, 256, 0, stream>>>(Opart, abuf);
  gemm_bt<64, true, false, false><<<dim3(EE / 64, TOK / 128), 256, 0, stream>>>(
      abuf, w2T, b_out, d_out, nullptr, TOK, EE, EE);
}